// Round 1
// baseline (600.652 us; speedup 1.0000x reference)
//
#include <hip/hip_runtime.h>

typedef unsigned short u16;
typedef unsigned int   u32;
typedef __bf16 bf16x8 __attribute__((ext_vector_type(8)));
typedef float  f32x4  __attribute__((ext_vector_type(4)));
typedef u32    u32x4  __attribute__((ext_vector_type(4)));

#define NS 256              // samples (M)
#define KF 10000            // features (K)
#define KP 10048            // padded K (multiple of 64)
#define NO 15000            // outputs (N)
#define NP 15104            // padded N = 118*128
#define BM 256
#define BN 128
#define BK 32
#define KHALF (KP/2)        // 5024
#define NSTEPS (KHALF/BK)   // 157
#define COVR 150
#define NA 100

// ---------------- prep: BatchNorm affine + fp32 -> bf16 hi/lo split ----------------
__global__ void k_prep_x(const float* __restrict__ x, const float* __restrict__ gamma,
                         const float* __restrict__ beta, const float* __restrict__ rmean,
                         const float* __restrict__ rvar,
                         u16* __restrict__ xnh, u16* __restrict__ xnl)
{
    int k = blockIdx.x * 256 + threadIdx.x;
    int s = blockIdx.y;
    if (k >= KP) return;
    float v = 0.0f;
    if (k < KF) {
        float xv = x[(size_t)s * KF + k];
        v = (xv - rmean[k]) * (gamma[k] * rsqrtf(rvar[k] + 1e-5f)) + beta[k];
    }
    u32 bits = __float_as_uint(v);
    u32 hb   = bits & 0xffff0000u;              // truncate -> hi bf16
    float lo = v - __uint_as_float(hb);         // exact residual (<=16 sig bits)
    xnh[(size_t)s * KP + k] = (u16)(hb >> 16);
    xnl[(size_t)s * KP + k] = (u16)(__float_as_uint(lo) >> 16);
}

__device__ __forceinline__ void split_pack(float v0, float v1, u32& hp, u32& lp)
{
    u32 b0 = __float_as_uint(v0), b1 = __float_as_uint(v1);
    u32 h0 = b0 & 0xffff0000u,   h1 = b1 & 0xffff0000u;
    hp = (h0 >> 16) | h1;
    float r0 = v0 - __uint_as_float(h0);
    float r1 = v1 - __uint_as_float(h1);
    lp = (__float_as_uint(r0) >> 16) | (__float_as_uint(r1) & 0xffff0000u);
}

// ---------------- GEMM: Yp[ks] = Xn * W^T (3-term bf16 split), split-K=2 ----------------
// block: 512 thr (8 waves, 4M x 2N, wave tile 64x64), tiles BM=256 x BN=128, BK=32.
// LDS 96KB: double-buffered Ah/Al/Bh/Bl with XOR swizzle (chunk ^= (row>>1)&3).
__global__ __launch_bounds__(512, 2) void k_gemm(
    const u16* __restrict__ xnh, const u16* __restrict__ xnl,
    const float* __restrict__ W, float* __restrict__ Yp)
{
    __shared__ u16 Ah[2][BM * BK];
    __shared__ u16 Al[2][BM * BK];
    __shared__ u16 Bh[2][BN * BK];
    __shared__ u16 Bl[2][BN * BK];

    const int t    = threadIdx.x;
    const int n0   = blockIdx.x * BN;
    const int ks   = blockIdx.y;
    const int kbeg = ks * KHALF;

    // staging: linear LDS slot t (and t+512 for A) <- pre-swizzled global chunk
    const int rA0 = t >> 2;
    const int rA1 = rA0 + 128;
    const int uA  = t & 3;
    const int cA0 = uA ^ ((rA0 >> 1) & 3);
    const int cA1 = uA ^ ((rA1 >> 1) & 3);
    const size_t eA0 = (size_t)rA0 * KP + cA0 * 8;
    const size_t eA1 = (size_t)rA1 * KP + cA1 * 8;

    const int rB  = t >> 2;
    const int cB  = (t & 3) ^ ((rB >> 1) & 3);
    const int oW  = n0 + rB;
    const bool oOk = (oW < NO);
    const size_t eW = (size_t)(oOk ? oW : 0) * KF + cB * 8;

    // compute-side lane constants
    const int lane = t & 63;
    const int w    = t >> 6;
    const int wm   = w & 3;   // 4 M-groups of 64
    const int wn   = w >> 2;  // 2 N-groups of 64
    const int l15  = lane & 15;
    const int lc   = lane >> 4;
    const int q    = (l15 >> 1) & 3;
    const int eoff = l15 * BK + ((lc ^ q) << 3);   // swizzled element offset

    f32x4 acc[4][4];
#pragma unroll
    for (int m = 0; m < 4; ++m)
#pragma unroll
        for (int n = 0; n < 4; ++n) { acc[m][n][0]=0.f; acc[m][n][1]=0.f; acc[m][n][2]=0.f; acc[m][n][3]=0.f; }

    // prologue: stage step 0 into buffer 0
    {
        const int k0 = kbeg;
        u32x4 a0 = *(const u32x4*)(xnh + eA0 + k0);
        u32x4 a1 = *(const u32x4*)(xnh + eA1 + k0);
        u32x4 g0 = *(const u32x4*)(xnl + eA0 + k0);
        u32x4 g1 = *(const u32x4*)(xnl + eA1 + k0);
        const bool okk = oOk && (k0 + cB * 8 + 8 <= KF);
        const size_t wofs = okk ? (eW + k0) : 0;
        f32x4 w0 = *(const f32x4*)(W + wofs);
        f32x4 w1 = *(const f32x4*)(W + wofs + 4);
        const float msk = okk ? 1.f : 0.f;
        w0 *= msk; w1 *= msk;
        u32 h0,p0,h1,p1,h2,p2,h3,p3;
        split_pack(w0[0], w0[1], h0, p0);
        split_pack(w0[2], w0[3], h1, p1);
        split_pack(w1[0], w1[1], h2, p2);
        split_pack(w1[2], w1[3], h3, p3);
        u32x4 hv, lv; hv[0]=h0; hv[1]=h1; hv[2]=h2; hv[3]=h3; lv[0]=p0; lv[1]=p1; lv[2]=p2; lv[3]=p3;
        ((u32x4*)Ah[0])[t]       = a0;
        ((u32x4*)Ah[0])[t + 512] = a1;
        ((u32x4*)Al[0])[t]       = g0;
        ((u32x4*)Al[0])[t + 512] = g1;
        ((u32x4*)Bh[0])[t] = hv;
        ((u32x4*)Bl[0])[t] = lv;
    }

    int buf = 0;
#pragma unroll 1
    for (int step = 0; step < NSTEPS; ++step) {
        __syncthreads();

        const bool hasNext = (step + 1) < NSTEPS;
        u32x4 a0, a1, g0, g1; f32x4 w0, w1; float msk = 0.f;
        if (hasNext) {
            const int k0 = kbeg + (step + 1) * BK;
            a0 = *(const u32x4*)(xnh + eA0 + k0);
            a1 = *(const u32x4*)(xnh + eA1 + k0);
            g0 = *(const u32x4*)(xnl + eA0 + k0);
            g1 = *(const u32x4*)(xnl + eA1 + k0);
            const bool okk = oOk && (k0 + cB * 8 + 8 <= KF);
            const size_t wofs = okk ? (eW + k0) : 0;
            w0 = *(const f32x4*)(W + wofs);
            w1 = *(const f32x4*)(W + wofs + 4);
            msk = okk ? 1.f : 0.f;
        }

        const u16* AhL = Ah[buf]; const u16* AlL = Al[buf];
        const u16* BhL = Bh[buf]; const u16* BlL = Bl[buf];
        bf16x8 fah[4], fal[4], fbh[4], fbl[4];
#pragma unroll
        for (int m = 0; m < 4; ++m) {
            const int off = (wm * 64 + m * 16) * BK + eoff;
            fah[m] = *(const bf16x8*)(AhL + off);
            fal[m] = *(const bf16x8*)(AlL + off);
        }
#pragma unroll
        for (int n = 0; n < 4; ++n) {
            const int off = (wn * 64 + n * 16) * BK + eoff;
            fbh[n] = *(const bf16x8*)(BhL + off);
            fbl[n] = *(const bf16x8*)(BlL + off);
        }
#pragma unroll
        for (int m = 0; m < 4; ++m)
#pragma unroll
            for (int n = 0; n < 4; ++n) {
                acc[m][n] = __builtin_amdgcn_mfma_f32_16x16x32_bf16(fah[m], fbh[n], acc[m][n], 0, 0, 0);
                acc[m][n] = __builtin_amdgcn_mfma_f32_16x16x32_bf16(fah[m], fbl[n], acc[m][n], 0, 0, 0);
                acc[m][n] = __builtin_amdgcn_mfma_f32_16x16x32_bf16(fal[m], fbh[n], acc[m][n], 0, 0, 0);
            }

        if (hasNext) {
            const int nb = buf ^ 1;
            w0 *= msk; w1 *= msk;
            u32 h0,p0,h1,p1,h2,p2,h3,p3;
            split_pack(w0[0], w0[1], h0, p0);
            split_pack(w0[2], w0[3], h1, p1);
            split_pack(w1[0], w1[1], h2, p2);
            split_pack(w1[2], w1[3], h3, p3);
            u32x4 hv, lv; hv[0]=h0; hv[1]=h1; hv[2]=h2; hv[3]=h3; lv[0]=p0; lv[1]=p1; lv[2]=p2; lv[3]=p3;
            ((u32x4*)Ah[nb])[t]       = a0;
            ((u32x4*)Ah[nb])[t + 512] = a1;
            ((u32x4*)Al[nb])[t]       = g0;
            ((u32x4*)Al[nb])[t + 512] = g1;
            ((u32x4*)Bh[nb])[t] = hv;
            ((u32x4*)Bl[nb])[t] = lv;
            buf = nb;
        }
    }

    // epilogue: C/D layout col = lane&15, row = (lane>>4)*4 + reg
    const int rowb = wm * 64 + lc * 4;
    const int colb = n0 + wn * 64 + l15;
#pragma unroll
    for (int m = 0; m < 4; ++m)
#pragma unroll
        for (int n = 0; n < 4; ++n) {
            const size_t base = ((size_t)(ks * NS + rowb + m * 16)) * NP + colb + n * 16;
            Yp[base]          = acc[m][n][0];
            Yp[base + NP]     = acc[m][n][1];
            Yp[base + 2*NP]   = acc[m][n][2];
            Yp[base + 3*NP]   = acc[m][n][3];
        }
}

// ---------------- reduce split-K partials + bias + relu ----------------
__global__ void k_reduce(const float* __restrict__ Yp, const float* __restrict__ bias,
                         float* __restrict__ Y)
{
    int o = blockIdx.x * 256 + threadIdx.x;
    int s = blockIdx.y;
    if (o >= NO) return;
    size_t i = (size_t)s * NP + o;
    float v = Yp[i] + Yp[(size_t)NS * NP + i] + bias[o];
    Y[i] = fmaxf(v, 0.0f);
}

// ---------------- per-sample: cov -> Cholesky -> w = A^-1 1 / (1^T A^-1 1) ----------------
__global__ __launch_bounds__(256) void k_solve(const float* __restrict__ Y, float* __restrict__ out)
{
    __shared__ float Ash[104 * 113];
    __shared__ float Msh[30 * 112];
    __shared__ float mu[104];
    __shared__ float yv[104];
    __shared__ float red[8];

    const int s = blockIdx.x;
    const int t = threadIdx.x;
    const float* Ys = Y + (size_t)s * NP;

    // column means
    if (t < NA) {
        float a = 0.f;
        for (int r = 0; r < COVR; ++r) a += Ys[r * NA + t];
        mu[t] = a * (1.0f / COVR);
    }
    __syncthreads();

    // A = m^T m / 149, built in 5 chunks of 30 rows; thread (ai,bj) owns 8x7 output tile
    const int ai = t >> 4;
    const int bj = t & 15;
    float acc[8][7];
#pragma unroll
    for (int i = 0; i < 8; ++i)
#pragma unroll
        for (int j = 0; j < 7; ++j) acc[i][j] = 0.f;

    for (int c = 0; c < 5; ++c) {
        for (int idx = t; idx < 30 * 112; idx += 256) {
            int r = idx / 112, j = idx - r * 112;
            float v = 0.f;
            if (j < NA) v = Ys[(c * 30 + r) * NA + j] - mu[j];
            Msh[idx] = v;
        }
        __syncthreads();
        if (ai < 13) {
            for (int r = 0; r < 30; ++r) {
                float mi[8], mj[7];
#pragma unroll
                for (int i = 0; i < 8; ++i) mi[i] = Msh[r * 112 + ai * 8 + i];
#pragma unroll
                for (int j = 0; j < 7; ++j) mj[j] = Msh[r * 112 + bj * 7 + j];
#pragma unroll
                for (int i = 0; i < 8; ++i)
#pragma unroll
                    for (int j = 0; j < 7; ++j) acc[i][j] += mi[i] * mj[j];
            }
        }
        __syncthreads();
    }
    if (ai < 13) {
#pragma unroll
        for (int i = 0; i < 8; ++i)
#pragma unroll
            for (int j = 0; j < 7; ++j)
                Ash[(ai * 8 + i) * 113 + (bj * 7 + j)] = acc[i][j] * (1.0f / 149.0f);
    }
    __syncthreads();

    // in-place Cholesky (lower), right-looking, column ownership
    for (int j = 0; j < NA; ++j) {
        if (t == 0) Ash[j * 113 + j] = sqrtf(Ash[j * 113 + j]);
        __syncthreads();
        const float dinv = 1.0f / Ash[j * 113 + j];
        if (t > j && t < NA) Ash[t * 113 + j] *= dinv;
        __syncthreads();
        if (t > j && t < NA) {
            const float ckj = Ash[t * 113 + j];
            for (int i = t; i < NA; ++i)
                Ash[i * 113 + t] -= Ash[i * 113 + j] * ckj;
        }
        __syncthreads();
    }

    // forward solve L y = 1
    if (t < 104) yv[t] = 1.0f;
    __syncthreads();
    for (int j = 0; j < NA; ++j) {
        if (t == 0) yv[j] = yv[j] / Ash[j * 113 + j];
        __syncthreads();
        const float yj = yv[j];
        if (t > j && t < NA) yv[t] -= Ash[t * 113 + j] * yj;
        __syncthreads();
    }
    // backward solve L^T u = y (in place)
    for (int j = NA - 1; j >= 0; --j) {
        if (t == 0) yv[j] = yv[j] / Ash[j * 113 + j];
        __syncthreads();
        const float uj = yv[j];
        if (t < j) yv[t] -= Ash[j * 113 + t] * uj;
        __syncthreads();
    }

    // normalize: w = u / sum(u)
    const float uval = (t < NA) ? yv[t] : 0.f;
    float v = uval;
    for (int off = 32; off > 0; off >>= 1) v += __shfl_down(v, off);
    if ((t & 63) == 0) red[t >> 6] = v;
    __syncthreads();
    const float tot = red[0] + red[1] + red[2] + red[3];
    const float inv = 1.0f / tot;
    if (t < NA) out[s * NA + t] = uval * inv;
}

// ---------------- launcher ----------------
extern "C" void kernel_launch(void* const* d_in, const int* in_sizes, int n_in,
                              void* d_out, int out_size, void* d_ws, size_t ws_size,
                              hipStream_t stream)
{
    const float* x     = (const float*)d_in[0];
    const float* gamma = (const float*)d_in[1];
    const float* beta  = (const float*)d_in[2];
    const float* rm    = (const float*)d_in[3];
    const float* rv    = (const float*)d_in[4];
    const float* W     = (const float*)d_in[5];
    const float* b     = (const float*)d_in[6];
    float* out = (float*)d_out;

    char* ws = (char*)d_ws;
    u16*   xnh = (u16*)ws;                              // 256*10048*2  = 5,144,576 B
    u16*   xnl = (u16*)(ws + 5144576);                  // 5,144,576 B
    float* Yp  = (float*)(ws + 10289152);               // 2*256*15104*4 = 30,932,992 B
    float* Y   = (float*)(ws + 41222144);               // 256*15104*4 = 15,466,496 B
    (void)in_sizes; (void)n_in; (void)out_size; (void)ws_size;

    k_prep_x<<<dim3(40, NS), 256, 0, stream>>>(x, gamma, beta, rm, rv, xnh, xnl);
    k_gemm  <<<dim3(NP / BN, 2), 512, 0, stream>>>(xnh, xnl, W, Yp);
    k_reduce<<<dim3((NO + 255) / 256, NS), 256, 0, stream>>>(Yp, b, Y);
    k_solve <<<dim3(NS), 256, 0, stream>>>(Y, out);
}